// Round 10
// baseline (553.997 us; speedup 1.0000x reference)
//
#include <hip/hip_runtime.h>

#define NN 100000
#define NE 1600000
#define NF 256
#define HD 64
#define NC 32

#define NBK ((NN + 255) >> 8)      // 391 blocks of 256 nodes

__device__ __forceinline__ float lrelu02(float x) { return fmaxf(x, 0.2f * x); }

typedef __attribute__((ext_vector_type(8))) short bf16x8;
typedef __attribute__((ext_vector_type(4))) float f32x4;
typedef __attribute__((ext_vector_type(8))) _Float16 f16x8;

// round-to-nearest-even f32 -> bf16 (finite inputs)
__device__ __forceinline__ unsigned short f2bf(float f) {
    unsigned int u = __float_as_uint(f);
    unsigned int r = u + 0x7FFFu + ((u >> 16) & 1u);
    return (unsigned short)(r >> 16);
}
__device__ __forceinline__ float bf2f(unsigned short s) {
    return __uint_as_float(((unsigned int)s) << 16);
}

// ---------------- CSR build: direct global-atomic version ----------------
// Replaces the 4-kernel bucketed counting sort (two heavy LDS kernels) with:
// hist (1.7M L2 atomics on a 400KB counter array) -> 3-step 100k scan ->
// scatter (atomicAdd slot + random 4B write). Less total work; CSR content is
// permuted within each dst run (sum is commutative).

__global__ __launch_bounds__(256) void node_hist(const int* __restrict__ dst, int* __restrict__ dcount) {
    int i = blockIdx.x * 256 + threadIdx.x;
    if (i < NE) atomicAdd(&dcount[dst[i]], 1);
}

__global__ __launch_bounds__(256) void scan_local(const int* __restrict__ dcount,
                                                  int* __restrict__ lexcl, int* __restrict__ psum) {
    __shared__ int sh[256];
    int b = blockIdx.x, tid = threadIdx.x;
    int i = b * 256 + tid;
    int v = (i < NN) ? dcount[i] : 0;
    sh[tid] = v;
    __syncthreads();
    for (int d = 1; d < 256; d <<= 1) {
        int t = (tid >= d) ? sh[tid - d] : 0;
        __syncthreads();
        sh[tid] += t;
        __syncthreads();
    }
    if (i < NN) lexcl[i] = sh[tid] - v;
    if (tid == 255) psum[b] = sh[255];
}

__global__ void scan_block(const int* __restrict__ psum, int* __restrict__ pbase) {
    __shared__ int sh[512];
    int tid = threadIdx.x;
    int v = (tid < NBK) ? psum[tid] : 0;
    sh[tid] = v;
    __syncthreads();
    for (int d = 1; d < 512; d <<= 1) {
        int t = (tid >= d) ? sh[tid - d] : 0;
        __syncthreads();
        sh[tid] += t;
        __syncthreads();
    }
    if (tid < NBK) pbase[tid] = sh[tid] - v;
}

__global__ __launch_bounds__(256) void scan_final(const int* __restrict__ lexcl, const int* __restrict__ pbase,
                                                  int* __restrict__ offs, int* __restrict__ cur) {
    int i = blockIdx.x * 256 + threadIdx.x;
    if (i < NN) {
        int o = lexcl[i] + pbase[i >> 8];
        offs[i] = o;
        cur[i]  = o;
    }
    if (i == NN) offs[NN] = NE;
}

__global__ __launch_bounds__(256) void edge_scatter(const int* __restrict__ src, const int* __restrict__ dst,
                                                    int* __restrict__ cur, int* __restrict__ csr) {
    int i = blockIdx.x * 256 + threadIdx.x;
    if (i < NE) {
        int pos = atomicAdd(&cur[dst[i]], 1);
        csr[pos] = src[i];
    }
}

// ---------------- split-bf16 MFMA GEMM: A in registers, B in LDS, 2-wave blocks (unchanged) ----------------

template <int CIN, int COUT>
__global__ __launch_bounds__(128) void mfma_gemm(const float* __restrict__ in, const float* __restrict__ W,
                                                 const float* __restrict__ a_s, const float* __restrict__ a_d,
                                                 _Float16* __restrict__ hout, float* __restrict__ asv,
                                                 float* __restrict__ adv) {
    const int KC  = 32;
    const int BM  = 64;
    const int NCT = COUT / 16;       // col tiles: 4 (COUT=64) or 2 (COUT=32)
    const int NCH = CIN / KC;
    const int SPT = (4 * COUT) / 128;  // (kg,col) slots per thread: 2 or 1

    __shared__ unsigned short Bh[2][4 * COUT * 8];   // 8 / 4 KB
    __shared__ unsigned short Bl[2][4 * COUT * 8];

    int tid  = threadIdx.x;
    int lane = tid & 63;
    int wave = tid >> 6;             // 0..1
    int fr = lane & 15;              // free-dim index within 16-tile
    int kg = lane >> 4;              // k-group (0..3), 8 k each
    int n0base = blockIdx.x * BM;
    int rbase  = n0base + wave * 32;

    int scol[SPT], skg[SPT];
    #pragma unroll
    for (int i = 0; i < SPT; i++) {
        int s = tid + i * 128;
        scol[i] = s % COUT;
        skg[i]  = s / COUT;
    }

    float4 xr[4];
    float  wv[SPT][8];
    bf16x8 ah[2], al[2];

    f32x4 acc[2][NCT];
    #pragma unroll
    for (int rt = 0; rt < 2; rt++)
        #pragma unroll
        for (int ct = 0; ct < NCT; ct++) acc[rt][ct] = (f32x4){0.f, 0.f, 0.f, 0.f};

    auto load_A = [&](int k0) {
        #pragma unroll
        for (int rt = 0; rt < 2; rt++) {
            int gr = rbase + rt * 16 + fr;
            if (gr < NN) {
                const float* p = &in[(size_t)gr * CIN + k0 + kg * 8];
                xr[rt * 2 + 0] = *(const float4*)p;
                xr[rt * 2 + 1] = *(const float4*)(p + 4);
            } else {
                xr[rt * 2 + 0] = make_float4(0.f, 0.f, 0.f, 0.f);
                xr[rt * 2 + 1] = make_float4(0.f, 0.f, 0.f, 0.f);
            }
        }
    };
    auto conv_A = [&]() {
        #pragma unroll
        for (int rt = 0; rt < 2; rt++) {
            const float* v = (const float*)&xr[rt * 2];
            unsigned short hs[8], ls[8];
            #pragma unroll
            for (int j = 0; j < 8; j++) {
                hs[j] = f2bf(v[j]);
                ls[j] = f2bf(v[j] - bf2f(hs[j]));
            }
            ah[rt] = *(bf16x8*)hs;
            al[rt] = *(bf16x8*)ls;
        }
    };
    auto load_B = [&](int k0) {
        #pragma unroll
        for (int i = 0; i < SPT; i++)
            #pragma unroll
            for (int j = 0; j < 8; j++)
                wv[i][j] = W[(size_t)(k0 + skg[i] * 8 + j) * COUT + scol[i]];
    };
    auto write_B = [&](int buf) {
        #pragma unroll
        for (int i = 0; i < SPT; i++) {
            unsigned short hs[8], ls[8];
            #pragma unroll
            for (int j = 0; j < 8; j++) {
                hs[j] = f2bf(wv[i][j]);
                ls[j] = f2bf(wv[i][j] - bf2f(hs[j]));
            }
            int idx = (skg[i] * COUT + scol[i]) * 8;
            *(uint4*)&Bh[buf][idx] = *(uint4*)hs;
            *(uint4*)&Bl[buf][idx] = *(uint4*)ls;
        }
    };
    auto do_mfma = [&](int buf) {
        #pragma unroll
        for (int ct = 0; ct < NCT; ct++) {
            int col = ct * 16 + fr;
            bf16x8 bh = *(const bf16x8*)&Bh[buf][(kg * COUT + col) * 8];
            bf16x8 bl = *(const bf16x8*)&Bl[buf][(kg * COUT + col) * 8];
            #pragma unroll
            for (int rt = 0; rt < 2; rt++) {
                acc[rt][ct] = __builtin_amdgcn_mfma_f32_16x16x32_bf16(ah[rt], bh, acc[rt][ct], 0, 0, 0);
                acc[rt][ct] = __builtin_amdgcn_mfma_f32_16x16x32_bf16(ah[rt], bl, acc[rt][ct], 0, 0, 0);
                acc[rt][ct] = __builtin_amdgcn_mfma_f32_16x16x32_bf16(al[rt], bh, acc[rt][ct], 0, 0, 0);
            }
        }
    };

    load_A(0);
    load_B(0);
    conv_A();
    write_B(0);
    __syncthreads();

    for (int t = 0; t < NCH; t++) {
        int cur = t & 1;
        if (t + 1 < NCH) {
            load_A((t + 1) * KC);
            load_B((t + 1) * KC);
        }
        do_mfma(cur);
        if (t + 1 < NCH) {
            write_B(cur ^ 1);
            conv_A();
            __syncthreads();
        }
    }

    float As_l[NCT], Ad_l[NCT];
    #pragma unroll
    for (int ct = 0; ct < NCT; ct++) {
        As_l[ct] = a_s[ct * 16 + fr];
        Ad_l[ct] = a_d[ct * 16 + fr];
    }
    #pragma unroll
    for (int rt = 0; rt < 2; rt++) {
        #pragma unroll
        for (int r = 0; r < 4; r++) {
            int row = rbase + rt * 16 + kg * 4 + r;
            if (row < NN) {
                #pragma unroll
                for (int ct = 0; ct < NCT; ct++)
                    hout[(size_t)row * COUT + ct * 16 + fr] = (_Float16)acc[rt][ct][r];
            }
            float ps = 0.f, pd = 0.f;
            #pragma unroll
            for (int ct = 0; ct < NCT; ct++) {
                ps += acc[rt][ct][r] * As_l[ct];
                pd += acc[rt][ct][r] * Ad_l[ct];
            }
            #pragma unroll
            for (int off = 1; off < 16; off <<= 1) {
                ps += __shfl_xor(ps, off);
                pd += __shfl_xor(pd, off);
            }
            if (fr == 0 && row < NN) { asv[row] = ps; adv[row] = pd; }
        }
    }
}

// ---------------- fused aggregate: 16B/lane gather (unchanged) ----------------

template <int C, bool ACT>
__global__ __launch_bounds__(256) void gat_agg(const _Float16* __restrict__ h16, const float* __restrict__ asv,
                                               const float* __restrict__ adv, const int* __restrict__ offs,
                                               const int* __restrict__ csr,
                                               const float* __restrict__ bias, float* __restrict__ out) {
    const int LR = C / 8;            // lanes per row: 8 (C=64) or 4 (C=32)
    const int G  = 64 / LR;          // edges in flight: 8 or 16
    const f16x8* hh = (const f16x8*)h16;
    int lane = threadIdx.x & 63;
    int v = blockIdx.x * 4 + (threadIdx.x >> 6);
    int beg = offs[v], end = offs[v + 1];
    int g = lane / LR, r = lane % LR;
    float adv_v = adv[v];

    float acc[8] = {0.f, 0.f, 0.f, 0.f, 0.f, 0.f, 0.f, 0.f};
    float dsum = 0.f;
    #pragma unroll 4
    for (int e = beg + g; e < end; e += G) {
        int s = csr[e];
        float ww = __expf(lrelu02(asv[s] + adv_v));
        f16x8 hv = hh[(size_t)s * LR + r];
        dsum += ww;
        #pragma unroll
        for (int j = 0; j < 8; j++) acc[j] += ww * (float)hv[j];
    }
    #pragma unroll
    for (int off = LR; off < 64; off <<= 1) {
        #pragma unroll
        for (int j = 0; j < 8; j++) acc[j] += __shfl_xor(acc[j], off);
        dsum += __shfl_xor(dsum, off);
    }
    if (g == 0) {
        float selfw = __expf(lrelu02(asv[v] + adv_v));
        f16x8 hs = hh[(size_t)v * LR + r];
        #pragma unroll
        for (int j = 0; j < 8; j++) acc[j] += selfw * (float)hs[j];
        dsum += selfw;
        float inv = 1.f / (dsum + 1e-16f);
        float4 bb0 = ((const float4*)bias)[r * 2];
        float4 bb1 = ((const float4*)bias)[r * 2 + 1];
        float4 o0, o1;
        o0.x = acc[0] * inv + bb0.x; o0.y = acc[1] * inv + bb0.y;
        o0.z = acc[2] * inv + bb0.z; o0.w = acc[3] * inv + bb0.w;
        o1.x = acc[4] * inv + bb1.x; o1.y = acc[5] * inv + bb1.y;
        o1.z = acc[6] * inv + bb1.z; o1.w = acc[7] * inv + bb1.w;
        if (ACT) {
            o0.x = fmaxf(o0.x, 0.01f * o0.x); o0.y = fmaxf(o0.y, 0.01f * o0.y);
            o0.z = fmaxf(o0.z, 0.01f * o0.z); o0.w = fmaxf(o0.w, 0.01f * o0.w);
            o1.x = fmaxf(o1.x, 0.01f * o1.x); o1.y = fmaxf(o1.y, 0.01f * o1.y);
            o1.z = fmaxf(o1.z, 0.01f * o1.z); o1.w = fmaxf(o1.w, 0.01f * o1.w);
        }
        ((float4*)out)[(size_t)v * (C / 4) + r * 2]     = o0;
        ((float4*)out)[(size_t)v * (C / 4) + r * 2 + 1] = o1;
    }
}

// ---------------- launch ----------------

extern "C" void kernel_launch(void* const* d_in, const int* in_sizes, int n_in,
                              void* d_out, int out_size, void* d_ws, size_t ws_size,
                              hipStream_t stream) {
    const float* x   = (const float*)d_in[0];
    const int*   ei  = (const int*)d_in[1];
    const float* W1  = (const float*)d_in[2];
    const float* as1 = (const float*)d_in[3];
    const float* ad1 = (const float*)d_in[4];
    const float* b1  = (const float*)d_in[5];
    const float* W2  = (const float*)d_in[6];
    const float* as2 = (const float*)d_in[7];
    const float* ad2 = (const float*)d_in[8];
    const float* b2  = (const float*)d_in[9];
    const float* W3  = (const float*)d_in[10];
    const float* as3 = (const float*)d_in[11];
    const float* ad3 = (const float*)d_in[12];
    const float* b3  = (const float*)d_in[13];
    float* out = (float*)d_out;

    const int* srcp = ei;
    const int* dstp = ei + NE;

    char* w = (char*)d_ws;
    _Float16* h16 = (_Float16*)w;  w += sizeof(_Float16) * (size_t)NN * HD;
    float* featB = (float*)w;   w += sizeof(float) * (size_t)NN * HD;
    float* asv   = (float*)w;   w += sizeof(float) * NN;
    float* advv  = (float*)w;   w += sizeof(float) * NN;
    int* offs    = (int*)w;     w += sizeof(int) * (NN + 1);
    int* csr     = (int*)w;     w += sizeof(int) * (size_t)NE;
    int* dcount  = (int*)w;     w += sizeof(int) * NN;
    int* lexcl   = (int*)w;     w += sizeof(int) * NN;
    int* curp    = (int*)w;     w += sizeof(int) * NN;
    int* psum    = (int*)w;     w += sizeof(int) * NBK;
    int* pbase   = (int*)w;     w += sizeof(int) * NBK;

    const int GBM = (NN + 63) / 64;          // BM=64 -> 1563 blocks
    const int GBE = (NE + 255) / 256;        // 6250 blocks (edge-parallel)

    // CSR build (direct atomic; shared across all 3 layers)
    hipMemsetAsync(dcount, 0, sizeof(int) * NN, stream);
    node_hist<<<GBE, 256, 0, stream>>>(dstp, dcount);
    scan_local<<<NBK, 256, 0, stream>>>(dcount, lexcl, psum);
    scan_block<<<1, 512, 0, stream>>>(psum, pbase);
    scan_final<<<NBK + 1, 256, 0, stream>>>(lexcl, pbase, offs, curp);
    edge_scatter<<<GBE, 256, 0, stream>>>(srcp, dstp, curp, csr);

    // layer 1
    mfma_gemm<NF, HD><<<GBM, 128, 0, stream>>>(x, W1, as1, ad1, h16, asv, advv);
    gat_agg<HD, true><<<NN / 4, 256, 0, stream>>>(h16, asv, advv, offs, csr, b1, featB);

    // layer 2
    mfma_gemm<HD, HD><<<GBM, 128, 0, stream>>>(featB, W2, as2, ad2, h16, asv, advv);
    gat_agg<HD, true><<<NN / 4, 256, 0, stream>>>(h16, asv, advv, offs, csr, b2, featB);

    // layer 3
    mfma_gemm<HD, NC><<<GBM, 128, 0, stream>>>(featB, W3, as3, ad3, h16, asv, advv);
    gat_agg<NC, false><<<NN / 4, 256, 0, stream>>>(h16, asv, advv, offs, csr, b3, out);
}

// Round 11
// 421.927 us; speedup vs baseline: 1.3130x; 1.3130x over previous
//
#include <hip/hip_runtime.h>

#define NN 100000
#define NE 1600000
#define NF 256
#define HD 64
#define NC 32

#define BKS 8
#define NBK ((NN + 255) >> 8)      // 391 buckets of 256 nodes
#define CHUNK 4096                 // edges per bin_edges block
#define NBLK ((NE + CHUNK - 1) / CHUNK)  // 391

__device__ __forceinline__ float lrelu02(float x) { return fmaxf(x, 0.2f * x); }

typedef __attribute__((ext_vector_type(8))) short bf16x8;
typedef __attribute__((ext_vector_type(4))) float f32x4;
typedef __attribute__((ext_vector_type(8))) _Float16 f16x8;

// round-to-nearest-even f32 -> bf16 (finite inputs)
__device__ __forceinline__ unsigned short f2bf(float f) {
    unsigned int u = __float_as_uint(f);
    unsigned int r = u + 0x7FFFu + ((u >> 16) & 1u);
    return (unsigned short)(r >> 16);
}
__device__ __forceinline__ float bf2f(unsigned short s) {
    return __uint_as_float(((unsigned int)s) << 16);
}

// ---------------- CSR build via bucketed counting sort (packed edges: (src<<8)|dstlocal) ----------------

__global__ __launch_bounds__(256) void bucket_hist(const int* __restrict__ dst, int* __restrict__ gcnt) {
    __shared__ int hist[NBK];
    int tid = threadIdx.x;
    for (int i = tid; i < NBK; i += 256) hist[i] = 0;
    __syncthreads();
    int base = blockIdx.x * CHUNK;
    #pragma unroll
    for (int k = 0; k < CHUNK / 256; k++) {
        int i = base + k * 256 + tid;
        if (i < NE) atomicAdd(&hist[dst[i] >> BKS], 1);
    }
    __syncthreads();
    for (int i = tid; i < NBK; i += 256) if (hist[i]) atomicAdd(&gcnt[i], hist[i]);
}

__global__ void bucket_scan(const int* __restrict__ gcnt, int* __restrict__ gbase, int* __restrict__ gcur) {
    __shared__ int sh[512];
    int tid = threadIdx.x;
    int v = (tid < NBK) ? gcnt[tid] : 0;
    sh[tid] = v;
    __syncthreads();
    for (int d = 1; d < 512; d <<= 1) {
        int t = (tid >= d) ? sh[tid - d] : 0;
        __syncthreads();
        sh[tid] += t;
        __syncthreads();
    }
    if (tid < NBK) { int ex = sh[tid] - v; gbase[tid] = ex; gcur[tid] = ex; }
}

__global__ __launch_bounds__(256) void bin_edges(const int* __restrict__ src, const int* __restrict__ dst,
                                                 int* __restrict__ gcur, unsigned int* __restrict__ ebuf) {
    __shared__ int hist[NBK];
    __shared__ int excl[NBK];
    __shared__ int runbase[NBK];
    __shared__ int ssum[256];
    __shared__ unsigned int sorted[CHUNK];     // 16 KB (packed edges)
    __shared__ unsigned short sortedb[CHUNK];  // 8 KB (bucket ids)
    int tid = threadIdx.x;
    int base = blockIdx.x * CHUNK;
    int n = NE - base; if (n > CHUNK) n = CHUNK;

    for (int i = tid; i < NBK; i += 256) hist[i] = 0;
    __syncthreads();

    unsigned int pk[CHUNK / 256];
    int bk[CHUNK / 256];
    #pragma unroll
    for (int k = 0; k < CHUNK / 256; k++) {
        int i = base + k * 256 + tid;
        if (i < NE) {
            int s = src[i], d = dst[i];
            pk[k] = ((unsigned int)s << 8) | ((unsigned int)d & 255u);
            bk[k] = d >> BKS;
            atomicAdd(&hist[bk[k]], 1);
        } else bk[k] = -1;
    }
    __syncthreads();
    int h0 = (2 * tid < NBK) ? hist[2 * tid] : 0;
    int h1 = (2 * tid + 1 < NBK) ? hist[2 * tid + 1] : 0;
    ssum[tid] = h0 + h1;
    __syncthreads();
    for (int d = 1; d < 256; d <<= 1) {
        int t = (tid >= d) ? ssum[tid - d] : 0;
        __syncthreads();
        ssum[tid] += t;
        __syncthreads();
    }
    int pref = ssum[tid] - (h0 + h1);
    if (2 * tid < NBK) excl[2 * tid] = pref;
    if (2 * tid + 1 < NBK) excl[2 * tid + 1] = pref + h0;
    for (int b = tid; b < NBK; b += 256) {
        int c = hist[b];
        runbase[b] = c ? atomicAdd(&gcur[b], c) : 0;
    }
    __syncthreads();
    #pragma unroll
    for (int k = 0; k < CHUNK / 256; k++) {
        if (bk[k] >= 0) {
            int r = atomicAdd(&excl[bk[k]], 1);
            sorted[r] = pk[k];
            sortedb[r] = (unsigned short)bk[k];
        }
    }
    __syncthreads();
    for (int i = tid; i < n; i += 256) {
        int b = sortedb[i];
        int local_rank = i - (excl[b] - hist[b]);
        ebuf[runbase[b] + local_rank] = sorted[i];
    }
}

__global__ __launch_bounds__(256) void bucket_csr(const unsigned int* __restrict__ ebuf, const int* __restrict__ gbase,
                                                  const int* __restrict__ gcnt,
                                                  int* __restrict__ offs, int* __restrict__ csr) {
    __shared__ int hist[256], cur[256], ssum[256];
    int b = blockIdx.x, tid = threadIdx.x;
    int ebeg = gbase[b], cnt = gcnt[b];
    int node0 = b << BKS;
    hist[tid] = 0;
    __syncthreads();
    for (int i = ebeg + tid; i < ebeg + cnt; i += 256)
        atomicAdd(&hist[ebuf[i] & 255u], 1);
    __syncthreads();
    int v = hist[tid];
    ssum[tid] = v;
    __syncthreads();
    for (int d = 1; d < 256; d <<= 1) {
        int t = (tid >= d) ? ssum[tid - d] : 0;
        __syncthreads();
        ssum[tid] += t;
        __syncthreads();
    }
    int ex = ebeg + ssum[tid] - v;
    cur[tid] = ex;
    int nnode = NN - node0; if (nnode > 256) nnode = 256;
    if (tid < nnode) offs[node0 + tid] = ex;
    if (b == NBK - 1 && tid == nnode - 1) offs[NN] = ebeg + cnt;
    __syncthreads();
    for (int i = ebeg + tid; i < ebeg + cnt; i += 256) {
        unsigned int e = ebuf[i];
        int pos = atomicAdd(&cur[e & 255u], 1);
        csr[pos] = (int)(e >> 8);
    }
}

// ---------------- split-bf16 MFMA GEMM: BM=32, A in regs, B in LDS ----------------
// R7 structure with the tile halved: 2-wave blocks, each wave owns 16 rows (one
// 16-row MFMA tile). Grid 3125 -> 12.2 blocks/CU (LDS caps at 10) -> ~20 waves/CU,
// vs BM=64's grid-limited 12 waves/CU. Same total MFMA/load work; W re-reads
// double but W is 64KB and L2-resident.

template <int CIN, int COUT>
__global__ __launch_bounds__(128) void mfma_gemm(const float* __restrict__ in, const float* __restrict__ W,
                                                 const float* __restrict__ a_s, const float* __restrict__ a_d,
                                                 _Float16* __restrict__ hout, float* __restrict__ asv,
                                                 float* __restrict__ adv) {
    const int KC  = 32;
    const int BM  = 32;
    const int NCT = COUT / 16;       // col tiles: 4 (COUT=64) or 2 (COUT=32)
    const int NCH = CIN / KC;
    const int SPT = (4 * COUT) / 128;  // (kg,col) slots per thread: 2 or 1

    __shared__ unsigned short Bh[2][4 * COUT * 8];   // 8 / 4 KB
    __shared__ unsigned short Bl[2][4 * COUT * 8];

    int tid  = threadIdx.x;
    int lane = tid & 63;
    int wave = tid >> 6;             // 0..1
    int fr = lane & 15;              // free-dim index within 16-tile
    int kg = lane >> 4;              // k-group (0..3), 8 k each
    int rbase = blockIdx.x * BM + wave * 16;

    int scol[SPT], skg[SPT];
    #pragma unroll
    for (int i = 0; i < SPT; i++) {
        int s = tid + i * 128;
        scol[i] = s % COUT;
        skg[i]  = s / COUT;
    }

    float4 xr[2];                    // one row's 16 k values
    float  wv[SPT][8];
    bf16x8 ah, al;

    f32x4 acc[NCT];
    #pragma unroll
    for (int ct = 0; ct < NCT; ct++) acc[ct] = (f32x4){0.f, 0.f, 0.f, 0.f};

    auto load_A = [&](int k0) {
        int gr = rbase + fr;
        if (gr < NN) {
            const float* p = &in[(size_t)gr * CIN + k0 + kg * 8];
            xr[0] = *(const float4*)p;
            xr[1] = *(const float4*)(p + 4);
        } else {
            xr[0] = make_float4(0.f, 0.f, 0.f, 0.f);
            xr[1] = make_float4(0.f, 0.f, 0.f, 0.f);
        }
    };
    auto conv_A = [&]() {
        const float* v = (const float*)&xr[0];
        unsigned short hs[8], ls[8];
        #pragma unroll
        for (int j = 0; j < 8; j++) {
            hs[j] = f2bf(v[j]);
            ls[j] = f2bf(v[j] - bf2f(hs[j]));
        }
        ah = *(bf16x8*)hs;
        al = *(bf16x8*)ls;
    };
    auto load_B = [&](int k0) {
        #pragma unroll
        for (int i = 0; i < SPT; i++)
            #pragma unroll
            for (int j = 0; j < 8; j++)
                wv[i][j] = W[(size_t)(k0 + skg[i] * 8 + j) * COUT + scol[i]];
    };
    auto write_B = [&](int buf) {
        #pragma unroll
        for (int i = 0; i < SPT; i++) {
            unsigned short hs[8], ls[8];
            #pragma unroll
            for (int j = 0; j < 8; j++) {
                hs[j] = f2bf(wv[i][j]);
                ls[j] = f2bf(wv[i][j] - bf2f(hs[j]));
            }
            int idx = (skg[i] * COUT + scol[i]) * 8;
            *(uint4*)&Bh[buf][idx] = *(uint4*)hs;
            *(uint4*)&Bl[buf][idx] = *(uint4*)ls;
        }
    };
    auto do_mfma = [&](int buf) {
        #pragma unroll
        for (int ct = 0; ct < NCT; ct++) {
            int col = ct * 16 + fr;
            bf16x8 bh = *(const bf16x8*)&Bh[buf][(kg * COUT + col) * 8];
            bf16x8 bl = *(const bf16x8*)&Bl[buf][(kg * COUT + col) * 8];
            acc[ct] = __builtin_amdgcn_mfma_f32_16x16x32_bf16(ah, bh, acc[ct], 0, 0, 0);
            acc[ct] = __builtin_amdgcn_mfma_f32_16x16x32_bf16(ah, bl, acc[ct], 0, 0, 0);
            acc[ct] = __builtin_amdgcn_mfma_f32_16x16x32_bf16(al, bh, acc[ct], 0, 0, 0);
        }
    };

    load_A(0);
    load_B(0);
    conv_A();
    write_B(0);
    __syncthreads();

    for (int t = 0; t < NCH; t++) {
        int cur = t & 1;
        if (t + 1 < NCH) {
            load_A((t + 1) * KC);
            load_B((t + 1) * KC);
        }
        do_mfma(cur);
        if (t + 1 < NCH) {
            write_B(cur ^ 1);
            conv_A();
            __syncthreads();
        }
    }

    float As_l[NCT], Ad_l[NCT];
    #pragma unroll
    for (int ct = 0; ct < NCT; ct++) {
        As_l[ct] = a_s[ct * 16 + fr];
        Ad_l[ct] = a_d[ct * 16 + fr];
    }
    #pragma unroll
    for (int r = 0; r < 4; r++) {
        int row = rbase + kg * 4 + r;
        if (row < NN) {
            #pragma unroll
            for (int ct = 0; ct < NCT; ct++)
                hout[(size_t)row * COUT + ct * 16 + fr] = (_Float16)acc[ct][r];
        }
        float ps = 0.f, pd = 0.f;
        #pragma unroll
        for (int ct = 0; ct < NCT; ct++) {
            ps += acc[ct][r] * As_l[ct];
            pd += acc[ct][r] * Ad_l[ct];
        }
        #pragma unroll
        for (int off = 1; off < 16; off <<= 1) {
            ps += __shfl_xor(ps, off);
            pd += __shfl_xor(pd, off);
        }
        if (fr == 0 && row < NN) { asv[row] = ps; adv[row] = pd; }
    }
}

// ---------------- fused aggregate: 16B/lane gather (unchanged) ----------------

template <int C, bool ACT>
__global__ __launch_bounds__(256) void gat_agg(const _Float16* __restrict__ h16, const float* __restrict__ asv,
                                               const float* __restrict__ adv, const int* __restrict__ offs,
                                               const int* __restrict__ csr,
                                               const float* __restrict__ bias, float* __restrict__ out) {
    const int LR = C / 8;            // lanes per row: 8 (C=64) or 4 (C=32)
    const int G  = 64 / LR;          // edges in flight: 8 or 16
    const f16x8* hh = (const f16x8*)h16;
    int lane = threadIdx.x & 63;
    int v = blockIdx.x * 4 + (threadIdx.x >> 6);
    int beg = offs[v], end = offs[v + 1];
    int g = lane / LR, r = lane % LR;
    float adv_v = adv[v];

    float acc[8] = {0.f, 0.f, 0.f, 0.f, 0.f, 0.f, 0.f, 0.f};
    float dsum = 0.f;
    #pragma unroll 4
    for (int e = beg + g; e < end; e += G) {
        int s = csr[e];
        float ww = __expf(lrelu02(asv[s] + adv_v));
        f16x8 hv = hh[(size_t)s * LR + r];
        dsum += ww;
        #pragma unroll
        for (int j = 0; j < 8; j++) acc[j] += ww * (float)hv[j];
    }
    #pragma unroll
    for (int off = LR; off < 64; off <<= 1) {
        #pragma unroll
        for (int j = 0; j < 8; j++) acc[j] += __shfl_xor(acc[j], off);
        dsum += __shfl_xor(dsum, off);
    }
    if (g == 0) {
        float selfw = __expf(lrelu02(asv[v] + adv_v));
        f16x8 hs = hh[(size_t)v * LR + r];
        #pragma unroll
        for (int j = 0; j < 8; j++) acc[j] += selfw * (float)hs[j];
        dsum += selfw;
        float inv = 1.f / (dsum + 1e-16f);
        float4 bb0 = ((const float4*)bias)[r * 2];
        float4 bb1 = ((const float4*)bias)[r * 2 + 1];
        float4 o0, o1;
        o0.x = acc[0] * inv + bb0.x; o0.y = acc[1] * inv + bb0.y;
        o0.z = acc[2] * inv + bb0.z; o0.w = acc[3] * inv + bb0.w;
        o1.x = acc[4] * inv + bb1.x; o1.y = acc[5] * inv + bb1.y;
        o1.z = acc[6] * inv + bb1.z; o1.w = acc[7] * inv + bb1.w;
        if (ACT) {
            o0.x = fmaxf(o0.x, 0.01f * o0.x); o0.y = fmaxf(o0.y, 0.01f * o0.y);
            o0.z = fmaxf(o0.z, 0.01f * o0.z); o0.w = fmaxf(o0.w, 0.01f * o0.w);
            o1.x = fmaxf(o1.x, 0.01f * o1.x); o1.y = fmaxf(o1.y, 0.01f * o1.y);
            o1.z = fmaxf(o1.z, 0.01f * o1.z); o1.w = fmaxf(o1.w, 0.01f * o1.w);
        }
        ((float4*)out)[(size_t)v * (C / 4) + r * 2]     = o0;
        ((float4*)out)[(size_t)v * (C / 4) + r * 2 + 1] = o1;
    }
}

// ---------------- launch ----------------

extern "C" void kernel_launch(void* const* d_in, const int* in_sizes, int n_in,
                              void* d_out, int out_size, void* d_ws, size_t ws_size,
                              hipStream_t stream) {
    const float* x   = (const float*)d_in[0];
    const int*   ei  = (const int*)d_in[1];
    const float* W1  = (const float*)d_in[2];
    const float* as1 = (const float*)d_in[3];
    const float* ad1 = (const float*)d_in[4];
    const float* b1  = (const float*)d_in[5];
    const float* W2  = (const float*)d_in[6];
    const float* as2 = (const float*)d_in[7];
    const float* ad2 = (const float*)d_in[8];
    const float* b2  = (const float*)d_in[9];
    const float* W3  = (const float*)d_in[10];
    const float* as3 = (const float*)d_in[11];
    const float* ad3 = (const float*)d_in[12];
    const float* b3  = (const float*)d_in[13];
    float* out = (float*)d_out;

    const int* srcp = ei;
    const int* dstp = ei + NE;

    char* w = (char*)d_ws;
    _Float16* h16 = (_Float16*)w;  w += sizeof(_Float16) * (size_t)NN * HD;
    float* featB = (float*)w;   w += sizeof(float) * (size_t)NN * HD;
    float* asv   = (float*)w;   w += sizeof(float) * NN;
    float* advv  = (float*)w;   w += sizeof(float) * NN;
    int* offs    = (int*)w;     w += sizeof(int) * (NN + 1);
    int* csr     = (int*)w;     w += sizeof(int) * (size_t)NE;
    unsigned int* ebuf = (unsigned int*)w; w += sizeof(unsigned int) * (size_t)NE;
    int* gcnt    = (int*)w;     w += sizeof(int) * NBK;
    int* gbase   = (int*)w;     w += sizeof(int) * NBK;
    int* gcur    = (int*)w;     w += sizeof(int) * NBK;

    const int GBM = (NN + 31) / 32;   // BM=32 -> 3125 blocks

    // CSR build (bucketed counting sort; shared across all 3 layers)
    hipMemsetAsync(gcnt, 0, sizeof(int) * NBK, stream);
    bucket_hist<<<NBLK, 256, 0, stream>>>(dstp, gcnt);
    bucket_scan<<<1, 512, 0, stream>>>(gcnt, gbase, gcur);
    bin_edges<<<NBLK, 256, 0, stream>>>(srcp, dstp, gcur, ebuf);
    bucket_csr<<<NBK, 256, 0, stream>>>(ebuf, gbase, gcnt, offs, csr);

    // layer 1
    mfma_gemm<NF, HD><<<GBM, 128, 0, stream>>>(x, W1, as1, ad1, h16, asv, advv);
    gat_agg<HD, true><<<NN / 4, 256, 0, stream>>>(h16, asv, advv, offs, csr, b1, featB);

    // layer 2
    mfma_gemm<HD, HD><<<GBM, 128, 0, stream>>>(featB, W2, as2, ad2, h16, asv, advv);
    gat_agg<HD, true><<<NN / 4, 256, 0, stream>>>(h16, asv, advv, offs, csr, b2, featB);

    // layer 3
    mfma_gemm<HD, NC><<<GBM, 128, 0, stream>>>(featB, W3, as3, ad3, h16, asv, advv);
    gat_agg<NC, false><<<NN / 4, 256, 0, stream>>>(h16, asv, advv, offs, csr, b3, out);
}